// Round 2
// baseline (419.541 us; speedup 1.0000x reference)
//
#include <hip/hip_runtime.h>
#include <hip/hip_bf16.h>

#define TT 1000
#define CC 3
#define HH 64
#define WW 64
#define HW (HH * WW)           // 4096
#define CHW (CC * HW)          // 12288
#define NCHUNK 50
#define CLEN 20                // NCHUNK*CLEN == TT
#define RT 2                   // rows per spatial tile
#define NTILE (HH / RT)        // 32 tiles
#define FILL_N (CC * (RT + 2) * 66)  // 792 LDS fill elements

// out[0:CHW] = x[0:CHW]  (xT slice; d_out is poisoned before every call)
__global__ __launch_bounds__(256) void copy_xT_kernel(const float* __restrict__ x,
                                                      float* __restrict__ out) {
    int i = blockIdx.x * blockDim.x + threadIdx.x;
    if (i < CHW) out[i] = x[i];
}

// Fused conv + temb bias + et_coeff scale + chunk partial sums.
// block = 192 threads: tid = co*64 + c  (co = output channel, wave-uniform).
// Each block: one (chunk, 2-row tile); loops the chunk's 20 t's, staging the
// 3ch x 4row x 66col halo tile in LDS per t. Writes A[t] and chunk sums S[ch].
__global__ __launch_bounds__(192) void conv_sum_kernel(const float* __restrict__ xin,
                                                       const float* __restrict__ conv_w,
                                                       const float* __restrict__ temb,
                                                       const int* __restrict__ tarr,
                                                       const float* __restrict__ et_coeff,
                                                       float* __restrict__ A,
                                                       float* __restrict__ S) {
    const int ch   = blockIdx.x / NTILE;
    const int tile = blockIdx.x % NTILE;
    const int h0   = tile * RT;
    const int tid  = threadIdx.x;
    const int co   = tid >> 6;   // 0..2, uniform within each wave
    const int c    = tid & 63;

    __shared__ float xs[CC][RT + 2][72];   // 72 stride: padding + room for c+2

    // this thread's 27 weights (its output channel), kept in VGPRs
    float wgt[27];
    #pragma unroll
    for (int j = 0; j < 27; ++j) wgt[j] = conv_w[co * 27 + j];

    float sum[RT];
    #pragma unroll
    for (int r = 0; r < RT; ++r) sum[r] = 0.f;

    for (int i = 0; i < CLEN; ++i) {
        const int t = ch * CLEN + i;
        const float* xt = xin + (size_t)t * CHW;

        __syncthreads();   // protect xs from previous iteration's readers
        for (int k = tid; k < FILL_N; k += 192) {
            int row = k / 66;                 // 0 .. 3*(RT+2)-1
            int cc  = k - row * 66;
            int chn = row / (RT + 2);
            int rr  = row - chn * (RT + 2);
            int h = h0 + rr - 1;
            int w = cc - 1;
            float v = 0.f;
            if ((unsigned)h < HH && (unsigned)w < WW) v = xt[chn * HW + h * WW + w];
            xs[chn][rr][cc] = v;
        }
        __syncthreads();

        const float ec   = et_coeff[t];
        const float bias = temb[tarr[t] * CC + co];

        #pragma unroll
        for (int r = 0; r < RT; ++r) {
            float a = 0.f;
            #pragma unroll
            for (int ci = 0; ci < CC; ++ci)
                #pragma unroll
                for (int kh = 0; kh < 3; ++kh)
                    #pragma unroll
                    for (int kw = 0; kw < 3; ++kw)
                        a += xs[ci][r + kh][c + kw] * wgt[ci * 9 + kh * 3 + kw];
            float o = ec * (a + bias);
            A[(size_t)t * CHW + co * HW + (h0 + r) * WW + c] = o;
            sum[r] += o;
        }
    }

    #pragma unroll
    for (int r = 0; r < RT; ++r)
        S[(size_t)ch * CHW + co * HW + (h0 + r) * WW + c] = sum[r];
}

// in-place exclusive scan over the NCHUNK chunk totals, per position
__global__ __launch_bounds__(256) void offset_scan_kernel(float* __restrict__ S) {
    int pos = blockIdx.x * blockDim.x + threadIdx.x;
    if (pos >= CHW) return;
    float run = 0.f;
    #pragma unroll
    for (int ch = 0; ch < NCHUNK; ++ch) {
        float v = S[ch * CHW + pos];
        S[ch * CHW + pos] = run;
        run += v;
    }
}

// out[(t+1)*CHW + pos] = alpha_ratio[t]*xT[pos] + et_prevsum_coeff[t]*prefix(t,pos)
__global__ __launch_bounds__(256) void final_kernel(const float* __restrict__ A,
                                                    const float* __restrict__ S,
                                                    const float* __restrict__ xT,
                                                    const float* __restrict__ ar,
                                                    const float* __restrict__ epc,
                                                    float* __restrict__ out) {
    int idx = blockIdx.x * blockDim.x + threadIdx.x;   // NCHUNK*CHW
    if (idx >= NCHUNK * CHW) return;
    int pos = idx % CHW;
    int ch = idx / CHW;
    float acc = S[idx];
    float xv = xT[pos];
    const float* p = A + (size_t)ch * CLEN * CHW + pos;
    float* q = out + (size_t)(ch * CLEN + 1) * CHW + pos;
    #pragma unroll
    for (int i = 0; i < CLEN; ++i) {
        int t = ch * CLEN + i;
        acc += p[(size_t)i * CHW];
        q[(size_t)i * CHW] = ar[t] * xv + epc[t] * acc;
    }
}

extern "C" void kernel_launch(void* const* d_in, const int* in_sizes, int n_in,
                              void* d_out, int out_size, void* d_ws, size_t ws_size,
                              hipStream_t stream) {
    const float* x    = (const float*)d_in[0];   // (T+1, C, H, W)
    const int*   tarr = (const int*)  d_in[1];   // (T,)
    const float* ar   = (const float*)d_in[2];   // (T,1,1,1)
    const float* ec   = (const float*)d_in[3];   // (T,1,1,1)
    const float* epc  = (const float*)d_in[4];   // (T,1,1,1)
    const float* cw   = (const float*)d_in[5];   // (C,C,3,3)
    const float* temb = (const float*)d_in[6];   // (T,C)
    float* out = (float*)d_out;                  // (T+1, C, H, W)

    float* A = (float*)d_ws;                     // TT*CHW floats (49.15 MB)
    float* S = A + (size_t)TT * CHW;             // NCHUNK*CHW floats (2.46 MB)

    copy_xT_kernel<<<(CHW + 255) / 256, 256, 0, stream>>>(x, out);

    for (int it = 0; it < 3; ++it) {
        const float* xin = (it == 0) ? x : out;  // slices 0..T-1 of previous xt
        conv_sum_kernel<<<NCHUNK * NTILE, 192, 0, stream>>>(xin, cw, temb, tarr, ec, A, S);
        offset_scan_kernel<<<(CHW + 255) / 256, 256, 0, stream>>>(S);
        final_kernel<<<(NCHUNK * CHW + 255) / 256, 256, 0, stream>>>(A, S, x, ar, epc, out);
    }
}

// Round 3
// 267.939 us; speedup vs baseline: 1.5658x; 1.5658x over previous
//
#include <hip/hip_runtime.h>
#include <hip/hip_bf16.h>

#define TT 1000
#define CC 3
#define HH 64
#define WW 64
#define HW 4096
#define CHW 12288
#define CHW4 3072            // CHW / 4
#define NCHUNK 50
#define CLEN 20              // NCHUNK*CLEN == TT

// out[0:CHW] = x[0:CHW] (d_out is re-poisoned before every call)
__global__ __launch_bounds__(256) void copy_xT_kernel(const float4* __restrict__ x,
                                                      float4* __restrict__ out) {
    int i = blockIdx.x * 256 + threadIdx.x;
    if (i < CHW4) out[i] = x[i];
}

// A[t,c,h,w] = et_coeff[t] * (conv3x3(xin[t])[c,h,w] + temb[tarr[t], c])
// thread = (t, 2-row pair, 4-col group); all 3 output channels share the loads.
// 36 float4 loads + 6 float4 stores per 24 outputs; weights via scalar loads.
__global__ __launch_bounds__(256) void conv_kernel(const float* __restrict__ xin,
                                                   const float* __restrict__ cw,
                                                   const float* __restrict__ temb,
                                                   const int* __restrict__ tarr,
                                                   const float* __restrict__ ec,
                                                   float* __restrict__ A) {
    int idx = blockIdx.x * 256 + threadIdx.x;   // TT*32*16 = 512000 exactly
    int wi = idx & 15;
    int hp = (idx >> 4) & 31;
    int t  = idx >> 9;                          // block-uniform (512 = 2 blocks/t)
    int h0 = hp * 2;
    int w0 = wi * 4;
    const float* xt = xin + (size_t)t * CHW;

    float acc[2][CC][4];
    #pragma unroll
    for (int o = 0; o < 2; ++o)
        #pragma unroll
        for (int co = 0; co < CC; ++co)
            #pragma unroll
            for (int k = 0; k < 4; ++k) acc[o][co][k] = 0.f;

    const float4 Z = make_float4(0.f, 0.f, 0.f, 0.f);
    #pragma unroll
    for (int ch = 0; ch < CC; ++ch) {
        const float* xc = xt + ch * HW;
        #pragma unroll
        for (int j = 0; j < 4; ++j) {           // input row h0-1+j
            int h = h0 - 1 + j;
            bool hv = (unsigned)h < (unsigned)HH;
            const float* row = xc + h * WW + w0;
            float4 L = (hv && wi > 0)  ? *(const float4*)(row - 4) : Z;
            float4 M = (hv)            ? *(const float4*)(row)     : Z;
            float4 R = (hv && wi < 15) ? *(const float4*)(row + 4) : Z;
            float win[6] = {L.w, M.x, M.y, M.z, M.w, R.x};
            #pragma unroll
            for (int o = 0; o < 2; ++o) {
                const int kh = j - o;           // input row = (h0+o) + kh - 1
                if (kh >= 0 && kh <= 2) {
                    #pragma unroll
                    for (int co = 0; co < CC; ++co) {
                        float wa = cw[((co * CC + ch) * 3 + kh) * 3 + 0];
                        float wb = cw[((co * CC + ch) * 3 + kh) * 3 + 1];
                        float wc = cw[((co * CC + ch) * 3 + kh) * 3 + 2];
                        #pragma unroll
                        for (int k = 0; k < 4; ++k)
                            acc[o][co][k] += win[k] * wa + win[k + 1] * wb + win[k + 2] * wc;
                    }
                }
            }
        }
    }

    float e = ec[t];
    int tr = tarr[t];
    #pragma unroll
    for (int o = 0; o < 2; ++o)
        #pragma unroll
        for (int co = 0; co < CC; ++co) {
            float b = temb[tr * CC + co];
            float4 v = make_float4(e * (acc[o][co][0] + b), e * (acc[o][co][1] + b),
                                   e * (acc[o][co][2] + b), e * (acc[o][co][3] + b));
            *(float4*)(A + (size_t)t * CHW + co * HW + (h0 + o) * WW + w0) = v;
        }
}

// S[ch,pos] = sum of A over the chunk's 20 t's (float4 lanes)
__global__ __launch_bounds__(256) void chunk_sum_kernel(const float4* __restrict__ A,
                                                        float4* __restrict__ S) {
    int ch = blockIdx.x / 12;                   // block-uniform
    int pos4 = (blockIdx.x % 12) * 256 + threadIdx.x;
    const float4* p = A + (size_t)ch * CLEN * CHW4 + pos4;
    float4 acc = make_float4(0.f, 0.f, 0.f, 0.f);
    #pragma unroll
    for (int i = 0; i < CLEN; ++i) {
        float4 v = p[(size_t)i * CHW4];
        acc.x += v.x; acc.y += v.y; acc.z += v.z; acc.w += v.w;
    }
    S[(size_t)ch * CHW4 + pos4] = acc;
}

// in-place exclusive scan of chunk totals, per float4 lane
__global__ __launch_bounds__(256) void offset_scan_kernel(float4* __restrict__ S) {
    int pos4 = blockIdx.x * 256 + threadIdx.x;
    if (pos4 >= CHW4) return;
    float4 run = make_float4(0.f, 0.f, 0.f, 0.f);
    #pragma unroll
    for (int ch = 0; ch < NCHUNK; ++ch) {
        float4 v = S[ch * CHW4 + pos4];
        S[ch * CHW4 + pos4] = run;
        run.x += v.x; run.y += v.y; run.z += v.z; run.w += v.w;
    }
}

// out[t+1] = ar[t]*xT + epc[t]*(chunk_offset + local running sum)
__global__ __launch_bounds__(256) void final_kernel(const float4* __restrict__ A,
                                                    const float4* __restrict__ S,
                                                    const float4* __restrict__ xT,
                                                    const float* __restrict__ ar,
                                                    const float* __restrict__ epc,
                                                    float4* __restrict__ out) {
    int ch = blockIdx.x / 12;                   // block-uniform
    int pos4 = (blockIdx.x % 12) * 256 + threadIdx.x;
    float4 acc = S[(size_t)ch * CHW4 + pos4];
    float4 xv = xT[pos4];
    const float4* p = A + (size_t)ch * CLEN * CHW4 + pos4;
    float4* q = out + (size_t)(ch * CLEN + 1) * CHW4 + pos4;
    #pragma unroll
    for (int i = 0; i < CLEN; ++i) {
        int t = ch * CLEN + i;                  // block-uniform -> s_load a/e
        float4 v = p[(size_t)i * CHW4];
        acc.x += v.x; acc.y += v.y; acc.z += v.z; acc.w += v.w;
        float a = ar[t], e = epc[t];
        q[(size_t)i * CHW4] = make_float4(a * xv.x + e * acc.x, a * xv.y + e * acc.y,
                                          a * xv.z + e * acc.z, a * xv.w + e * acc.w);
    }
}

extern "C" void kernel_launch(void* const* d_in, const int* in_sizes, int n_in,
                              void* d_out, int out_size, void* d_ws, size_t ws_size,
                              hipStream_t stream) {
    const float* x    = (const float*)d_in[0];   // (T+1, C, H, W)
    const int*   tarr = (const int*)  d_in[1];   // (T,)
    const float* ar   = (const float*)d_in[2];   // (T,1,1,1)
    const float* ec   = (const float*)d_in[3];   // (T,1,1,1)
    const float* epc  = (const float*)d_in[4];   // (T,1,1,1)
    const float* cw   = (const float*)d_in[5];   // (C,C,3,3)
    const float* temb = (const float*)d_in[6];   // (T,C)
    float* out = (float*)d_out;                  // (T+1, C, H, W)

    float* A = (float*)d_ws;                     // TT*CHW floats (49.15 MB)
    float* S = A + (size_t)TT * CHW;             // NCHUNK*CHW floats (2.46 MB)

    copy_xT_kernel<<<12, 256, 0, stream>>>((const float4*)x, (float4*)out);

    for (int it = 0; it < 3; ++it) {
        const float* xin = (it == 0) ? x : out;  // slices 0..T-1 of previous xt
        conv_kernel<<<2000, 256, 0, stream>>>(xin, cw, temb, tarr, ec, A);
        chunk_sum_kernel<<<NCHUNK * 12, 256, 0, stream>>>((const float4*)A, (float4*)S);
        offset_scan_kernel<<<12, 256, 0, stream>>>((float4*)S);
        final_kernel<<<NCHUNK * 12, 256, 0, stream>>>((const float4*)A, (const float4*)S,
                                                      (const float4*)x, ar, epc, (float4*)out);
    }
}

// Round 4
// 253.107 us; speedup vs baseline: 1.6576x; 1.0586x over previous
//
#include <hip/hip_runtime.h>
#include <hip/hip_bf16.h>

#define TT 1000
#define CC 3
#define HH 64
#define WW 64
#define HW 4096
#define CHW 12288
#define CHW4 3072            // CHW / 4
#define NCHUNK 50
#define CLEN 20              // NCHUNK*CLEN == TT

// out[0:CHW] = x[0:CHW] (d_out is re-poisoned before every call)
__global__ __launch_bounds__(256) void copy_xT_kernel(const float4* __restrict__ x,
                                                      float4* __restrict__ out) {
    int i = blockIdx.x * 256 + threadIdx.x;
    if (i < CHW4) out[i] = x[i];
}

// A[t,c,h,w] = et_coeff[t] * (conv3x3(xin[t])[c,h,w] + temb[tarr[t], c])
// thread = (t, 2-row pair, 4-col group); 3 output channels share all loads.
// Only the aligned M float4 is loaded; halo columns come from neighbor lanes
// via shuffles (lane&15 == wi, so +-1 lane is the horizontally adjacent group).
__global__ __launch_bounds__(256) void conv_kernel(const float* __restrict__ xin,
                                                   const float* __restrict__ cw,
                                                   const float* __restrict__ temb,
                                                   const int* __restrict__ tarr,
                                                   const float* __restrict__ ec,
                                                   float* __restrict__ A) {
    int idx = blockIdx.x * 256 + threadIdx.x;   // TT*32*16 = 512000 exactly
    int wi = idx & 15;
    int hp = (idx >> 4) & 31;
    int t  = idx >> 9;                          // block-uniform (2 blocks/t)
    int h0 = hp * 2;
    int w0 = wi * 4;
    const float* xt = xin + (size_t)t * CHW;

    float acc[2][CC][4];
    #pragma unroll
    for (int o = 0; o < 2; ++o)
        #pragma unroll
        for (int co = 0; co < CC; ++co)
            #pragma unroll
            for (int k = 0; k < 4; ++k) acc[o][co][k] = 0.f;

    const float4 Z = make_float4(0.f, 0.f, 0.f, 0.f);
    #pragma unroll
    for (int ch = 0; ch < CC; ++ch) {
        const float* xc = xt + ch * HW;
        #pragma unroll
        for (int j = 0; j < 4; ++j) {           // input row h0-1+j
            int h = h0 - 1 + j;
            bool hv = (unsigned)h < (unsigned)HH;
            float4 M = hv ? *(const float4*)(xc + h * WW + w0) : Z;
            float left  = __shfl_up(M.w, 1);    // neighbor group's last col
            float right = __shfl_down(M.x, 1);  // neighbor group's first col
            if (wi == 0)  left  = 0.f;          // w = -1 boundary
            if (wi == 15) right = 0.f;          // w = 64 boundary
            float win[6] = {left, M.x, M.y, M.z, M.w, right};
            #pragma unroll
            for (int o = 0; o < 2; ++o) {
                const int kh = j - o;           // input row = (h0+o) + kh - 1
                if (kh >= 0 && kh <= 2) {
                    #pragma unroll
                    for (int co = 0; co < CC; ++co) {
                        float wa = cw[((co * CC + ch) * 3 + kh) * 3 + 0];
                        float wb = cw[((co * CC + ch) * 3 + kh) * 3 + 1];
                        float wc = cw[((co * CC + ch) * 3 + kh) * 3 + 2];
                        #pragma unroll
                        for (int k = 0; k < 4; ++k)
                            acc[o][co][k] += win[k] * wa + win[k + 1] * wb + win[k + 2] * wc;
                    }
                }
            }
        }
    }

    float e = ec[t];
    int tr = tarr[t];
    #pragma unroll
    for (int o = 0; o < 2; ++o)
        #pragma unroll
        for (int co = 0; co < CC; ++co) {
            float b = temb[tr * CC + co];
            float4 v = make_float4(e * (acc[o][co][0] + b), e * (acc[o][co][1] + b),
                                   e * (acc[o][co][2] + b), e * (acc[o][co][3] + b));
            *(float4*)(A + (size_t)t * CHW + co * HW + (h0 + o) * WW + w0) = v;
        }
}

// S[ch,pos] = sum of A over the chunk's 20 t's (float4 lanes)
__global__ __launch_bounds__(256) void chunk_sum_kernel(const float4* __restrict__ A,
                                                        float4* __restrict__ S) {
    int ch = blockIdx.x / 12;                   // block-uniform
    int pos4 = (blockIdx.x % 12) * 256 + threadIdx.x;
    const float4* p = A + (size_t)ch * CLEN * CHW4 + pos4;
    float4 acc = make_float4(0.f, 0.f, 0.f, 0.f);
    #pragma unroll
    for (int i = 0; i < CLEN; ++i) {
        float4 v = p[(size_t)i * CHW4];
        acc.x += v.x; acc.y += v.y; acc.z += v.z; acc.w += v.w;
    }
    S[(size_t)ch * CHW4 + pos4] = acc;
}

// in-place exclusive scan of chunk totals, per float4 lane
__global__ __launch_bounds__(256) void offset_scan_kernel(float4* __restrict__ S) {
    int pos4 = blockIdx.x * 256 + threadIdx.x;
    if (pos4 >= CHW4) return;
    float4 run = make_float4(0.f, 0.f, 0.f, 0.f);
    #pragma unroll
    for (int ch = 0; ch < NCHUNK; ++ch) {
        float4 v = S[ch * CHW4 + pos4];
        S[ch * CHW4 + pos4] = run;
        run.x += v.x; run.y += v.y; run.z += v.z; run.w += v.w;
    }
}

// out[t+1] = ar[t]*xT + epc[t]*(chunk_offset + local running sum)
__global__ __launch_bounds__(256) void final_kernel(const float4* __restrict__ A,
                                                    const float4* __restrict__ S,
                                                    const float4* __restrict__ xT,
                                                    const float* __restrict__ ar,
                                                    const float* __restrict__ epc,
                                                    float4* __restrict__ out) {
    int ch = blockIdx.x / 12;                   // block-uniform
    int pos4 = (blockIdx.x % 12) * 256 + threadIdx.x;
    float4 acc = S[(size_t)ch * CHW4 + pos4];
    float4 xv = xT[pos4];
    const float4* p = A + (size_t)ch * CLEN * CHW4 + pos4;
    float4* q = out + (size_t)(ch * CLEN + 1) * CHW4 + pos4;
    #pragma unroll
    for (int i = 0; i < CLEN; ++i) {
        int t = ch * CLEN + i;                  // block-uniform -> s_load
        float4 v = p[(size_t)i * CHW4];
        acc.x += v.x; acc.y += v.y; acc.z += v.z; acc.w += v.w;
        float a = ar[t], e = epc[t];
        q[(size_t)i * CHW4] = make_float4(a * xv.x + e * acc.x, a * xv.y + e * acc.y,
                                          a * xv.z + e * acc.z, a * xv.w + e * acc.w);
    }
}

extern "C" void kernel_launch(void* const* d_in, const int* in_sizes, int n_in,
                              void* d_out, int out_size, void* d_ws, size_t ws_size,
                              hipStream_t stream) {
    const float* x    = (const float*)d_in[0];   // (T+1, C, H, W)
    const int*   tarr = (const int*)  d_in[1];   // (T,)
    const float* ar   = (const float*)d_in[2];   // (T,1,1,1)
    const float* ec   = (const float*)d_in[3];   // (T,1,1,1)
    const float* epc  = (const float*)d_in[4];   // (T,1,1,1)
    const float* cw   = (const float*)d_in[5];   // (C,C,3,3)
    const float* temb = (const float*)d_in[6];   // (T,C)
    float* out = (float*)d_out;                  // (T+1, C, H, W)

    float* A = (float*)d_ws;                     // TT*CHW floats (49.15 MB)
    float* S = A + (size_t)TT * CHW;             // NCHUNK*CHW floats (2.46 MB)

    copy_xT_kernel<<<12, 256, 0, stream>>>((const float4*)x, (float4*)out);

    for (int it = 0; it < 3; ++it) {
        const float* xin = (it == 0) ? x : out;  // slices 0..T-1 of previous xt
        conv_kernel<<<2000, 256, 0, stream>>>(xin, cw, temb, tarr, ec, A);
        chunk_sum_kernel<<<NCHUNK * 12, 256, 0, stream>>>((const float4*)A, (float4*)S);
        offset_scan_kernel<<<12, 256, 0, stream>>>((float4*)S);
        final_kernel<<<NCHUNK * 12, 256, 0, stream>>>((const float4*)A, (const float4*)S,
                                                      (const float4*)x, ar, epc, (float4*)out);
    }
}